// Round 4
// baseline (112.413 us; speedup 1.0000x reference)
//
#include <hip/hip_runtime.h>
#include <cstdint>
#include <cstddef>

// HierarchicalDenseLayer: base = ctx @ Wcat (bf16 MFMA). One wave per block,
// 16 rows, FULL-K LDS staging via 32x contiguous 1KB global_load_lds (dense
// 32KB sequential stream per wave -> max DRAM row locality), two-phase
// counted vmcnt, per-row XOR swizzle for conflict-free ds_read_b128.

#define CTXD 512
#define NCOL 66          // 22 joints * 3
#define KT   16          // 512 / 32 k-steps
#define NT   5           // ceil(66/16) N-tiles (padded to 80)
#define RPB  16          // rows per block = 1 wave, 1 M-tile
#define LDS_STRIDE 67    // epilogue tile stride (66+1)

typedef __attribute__((ext_vector_type(8))) short  short8;  // 8 bf16
typedef __attribute__((ext_vector_type(4))) float  f32x4;   // MFMA accum

__device__ __forceinline__ unsigned short f2bf(float x) {
  unsigned u = __float_as_uint(x);
  return (unsigned short)((u + 0x7FFFu + ((u >> 16) & 1u)) >> 16);
}

__device__ __forceinline__ unsigned cvt2(float a, float b) {
  unsigned r;
  asm("v_cvt_pk_bf16_f32 %0, %1, %2" : "=v"(r) : "v"(a), "v"(b));
  return r;
}

__device__ __forceinline__ float tanhpi(float x) {
  // pi * tanh(x) = pi * (1 - 2/(e^{2x}+1)); safe at +/-inf
  float t = exp2f(x * 2.885390081777927f);
  return 3.1415926f - 6.2831852f * __builtin_amdgcn_rcpf(t + 1.0f);
}

// ---------------------------------------------------------------------------
// Prep: pack Wcat (512 x 66 -> pad 80) into MFMA B-frag order:
// wf[((kt*NT+nt)*64+lane)*8+j] = Wcat[kt*32 + (lane>>4)*8 + j][nt*16 + (lane&15)]
// ---------------------------------------------------------------------------
__global__ void prep_wfrag(const float* __restrict__ W0,
                           const float* __restrict__ W,
                           unsigned short* __restrict__ wf) {
  int idx = blockIdx.x * blockDim.x + threadIdx.x;
  if (idx >= KT * NT * 64 * 8) return;
  int j    = idx & 7;
  int lane = (idx >> 3) & 63;
  int rest = idx >> 9;
  int nt   = rest % NT;
  int kt   = rest / NT;
  int k    = kt * 32 + (lane >> 4) * 8 + j;
  int col  = nt * 16 + (lane & 15);
  float v = 0.f;
  if (col < 3)          v = W0[k * 3 + col];
  else if (col < NCOL)  v = W[(col / 3) * (515 * 3) + k * 3 + (col % 3)];
  wf[idx] = f2bf(v);
}

// ---------------------------------------------------------------------------
// Main kernel: 64 threads (1 wave), 16 rows per block, full-K staging.
// ---------------------------------------------------------------------------
__global__ __launch_bounds__(64) void hdl_main(
    const float* __restrict__ ctx,   // [B, 512]
    const float* __restrict__ b0,    // [3]
    const float* __restrict__ W,     // [22, 515, 3]
    const float* __restrict__ bflat, // [22*3]
    const unsigned short* __restrict__ wf,
    float* __restrict__ out)         // [B, 66]
{
  // 32 KB: staging [16 rows][512 floats] (XOR-swizzled 16B units);
  // epilogue reuses the first 16*67 floats as the output tile.
  __shared__ float smem[RPB * CTXD];

  const int lane = threadIdx.x;      // 0..63
  const int r16  = lane & 15;        // A-row within tile / D-col within tile
  const int kg   = lane >> 4;        // k-group 0..3
  const int rx   = r16 & 7;
  const long blockRow = (long)blockIdx.x * RPB;

  f32x4 acc[NT] = {};

  // Preload kt=0 B-frags: these 5 are the ONLY VMEM loads before the glls,
  // so the vmcnt(16) count below is exact.
  short8 bfr0[NT];
#pragma unroll
  for (int n = 0; n < NT; ++n)
    bfr0[n] = *(const short8*)(wf + (size_t)(n * 64 + lane) * 8);
  asm volatile("" ::: "memory");

  // 32 x 1KB fully-contiguous global_load_lds. h-major: first 16 insts cover
  // k[0,256) of all 16 rows. Source pre-swizzled (lane ^ (r&7)) per rule 21;
  // LDS dest stays linear. Each inst = one contiguous 1KB global segment.
#pragma unroll
  for (int h = 0; h < 2; ++h) {
#pragma unroll
    for (int r = 0; r < RPB; ++r) {
      const float* s = ctx + (blockRow + r) * CTXD + h * 256
                           + ((lane ^ (r & 7)) << 2);
      __builtin_amdgcn_global_load_lds(
          (const __attribute__((address_space(1))) void*)s,
          (__attribute__((address_space(3))) void*)(smem + r * CTXD + h * 256),
          16, 0, 0);
    }
    asm volatile("" ::: "memory");
  }

  // outstanding: 5 bfr0 (oldest) + 32 gll; retire bfr0 + all 16 h0 glls
  asm volatile("s_waitcnt vmcnt(16)" ::: "memory");

#pragma unroll
  for (int kt = 0; kt < KT; ++kt) {
    if (kt == 8)
      asm volatile("s_waitcnt vmcnt(0)" ::: "memory");   // h1 glls complete

    short8 bfr[NT];
    if (kt == 0) {
#pragma unroll
      for (int n = 0; n < NT; ++n) bfr[n] = bfr0[n];
    } else {
#pragma unroll
      for (int n = 0; n < NT; ++n)
        bfr[n] = *(const short8*)(wf + (size_t)((kt * NT + n) * 64 + lane) * 8);
    }

    // A-frag: global 16B-unit g of row r lives at LDS unit g ^ (r&7)
    const int g0 = kt * 8 + kg * 2;
    const char* rowb = (const char*)smem + r16 * 2048;
    float4 f0 = *(const float4*)(rowb + (size_t)((g0       ^ rx) << 4));
    float4 f1 = *(const float4*)(rowb + (size_t)(((g0 + 1) ^ rx) << 4));
    union { short8 s; unsigned u[4]; } A;
    A.u[0] = cvt2(f0.x, f0.y);
    A.u[1] = cvt2(f0.z, f0.w);
    A.u[2] = cvt2(f1.x, f1.y);
    A.u[3] = cvt2(f1.z, f1.w);
#pragma unroll
    for (int n = 0; n < NT; ++n)
      acc[n] = __builtin_amdgcn_mfma_f32_16x16x32_bf16(A.s, bfr[n], acc[n],
                                                       0, 0, 0);
  }
  __syncthreads();

  // bias loads live AFTER the counted waits (keeps vmcnt arithmetic exact)
  float bias[NT];
#pragma unroll
  for (int n = 0; n < NT; ++n) {
    int col = n * 16 + r16;
    bias[n] = (col < 3) ? b0[col] : ((col < NCOL) ? bflat[col] : 0.f);
  }

  // acc -> tile [16][67]. D layout: col = lane&15, row = (lane>>4)*4 + q
#pragma unroll
  for (int n = 0; n < NT; ++n) {
    int col = n * 16 + r16;
    if (col < NCOL) {
#pragma unroll
      for (int q = 0; q < 4; ++q)
        smem[(kg * 4 + q) * LDS_STRIDE + col] = acc[n][q] + bias[n];
    }
  }
  __syncthreads();

  // per-row kinematic chain (threads 0..15, one per row)
  if (lane < RPB) {
    float* row = smem + lane * LDS_STRIDE;
    float J[22][3];
#pragma unroll
    for (int cc = 0; cc < 3; ++cc) J[0][cc] = tanhpi(row[cc]);

    constexpr int EP[21] = {0,2,5,8, 0,1,4,7, 0,3,6,9,12, 9,14,17,19, 9,13,16,18};
    constexpr int EC[21] = {2,5,8,11, 1,4,7,10, 3,6,9,12,15, 14,17,19,21, 13,16,18,20};
#pragma unroll
    for (int e = 0; e < 21; ++e) {
      const int p  = EP[e];
      const int ch = EC[e];
      const float* wp = W + ch * 1545 + 1536;   // W[ch][512:515][:]
#pragma unroll
      for (int cc = 0; cc < 3; ++cc) {
        float s = row[3 * ch + cc];
        s += J[p][0] * wp[cc] + J[p][1] * wp[3 + cc] + J[p][2] * wp[6 + cc];
        J[ch][cc] = tanhpi(s);
      }
    }
#pragma unroll
    for (int jj = 0; jj < 22; ++jj)
#pragma unroll
      for (int cc = 0; cc < 3; ++cc) row[3 * jj + cc] = J[jj][cc];
  }
  __syncthreads();

  // contiguous store of the block's [16 x 66] output (1056 floats)
  const size_t outBase = (size_t)blockRow * NCOL;
  for (int i = lane; i < RPB * NCOL; i += 64) {
    int r  = i / NCOL;
    int cc = i - r * NCOL;
    out[outBase + i] = smem[r * LDS_STRIDE + cc];
  }
}

extern "C" void kernel_launch(void* const* d_in, const int* in_sizes, int n_in,
                              void* d_out, int out_size, void* d_ws, size_t ws_size,
                              hipStream_t stream) {
  const float* ctx  = (const float*)d_in[0];
  const float* W0   = (const float*)d_in[1];
  const float* b0   = (const float*)d_in[2];
  const float* W    = (const float*)d_in[3];
  const float* bfl  = (const float*)d_in[4];
  unsigned short* wf = (unsigned short*)d_ws;   // 80 KB packed weights

  int prep_elems = KT * NT * 64 * 8;            // 40960
  hipLaunchKernelGGL(prep_wfrag, dim3((prep_elems + 255) / 256), dim3(256), 0,
                     stream, W0, W, wf);

  int nrows = out_size / NCOL;                  // 131072
  hipLaunchKernelGGL(hdl_main, dim3(nrows / RPB), dim3(64), 0,
                     stream, ctx, b0, W, bfl, wf, (float*)d_out);
}